// Round 12
// baseline (22.375 us; speedup 1.0000x reference)
//
#include <hip/hip_runtime.h>
#include <math.h>

// out[b,m] = x[b,m] + f(y[b,m]),  y[b,m] = sum_n softmax(A_param)[m,n] * x[b,n]
// f(y) = b2 + sum_h relu(y*W1[h] + b1[h]) * W2[h]  -- piecewise-linear in y,
// approximated by a 512-bin secant table (alpha_k, beta_k); anchors identical
// to R7/R10/R11 (all passed absmax 0.03125).
//
// R12: A/B experiment isolating the per-block prologue + LDS structure.
//  - prep_kernel (1 block, ~free in-graph per R4/R5 A/B): writes softmax(A)
//    [36 floats] and the table [512 x f32x2] into d_ws.
//  - main kernel: ZERO LDS, ZERO barriers, ZERO prologue. One pair per thread,
//    3 loads -> eval -> 3 stores. A is read via uniform-address loads (compiler
//    scalarizes to s_load); the 4KB table is gathered straight from L2.
//    2048 blocks turn over continuously -> read and write streams interleave.

typedef float f32x2 __attribute__((ext_vector_type(2)));
typedef float f32x4 __attribute__((ext_vector_type(4)));

#define NN 6
#define HH 32
#define NB 512
#define YMIN  (-8.0f)
#define YSPAN (16.0f)
#define INVH  ((float)NB / YSPAN)   // 32.0
#define OFFS  (-YMIN * INVH)        // 256.0
#define BINW  (YSPAN / (float)NB)   // 0.03125

__device__ __forceinline__ f32x2 mk2(float a, float b) {
    f32x2 r; r.x = a; r.y = b; return r;
}

__device__ __forceinline__ f32x2 pk_fma(f32x2 a, f32x2 b, f32x2 c) {
#if __has_builtin(__builtin_elementwise_fma)
    return __builtin_elementwise_fma(a, b, c);
#else
    f32x2 r; r.x = fmaf(a.x, b.x, c.x); r.y = fmaf(a.y, b.y, c.y); return r;
#endif
}

// --- Kernel 1: softmax(A_param) + secant table into d_ws ---
// ws[0..35] = softmax(A); ws[64 + 2k, 64 + 2k + 1] = (alpha_k, beta_k).
__global__ void prep_kernel(const float* __restrict__ Ap,
                            const float* __restrict__ W1p,
                            const float* __restrict__ b1p,
                            const float* __restrict__ W2p,
                            const float* __restrict__ b2p,
                            float* __restrict__ ws) {
    const int tid = threadIdx.x;

    if (tid < NN) {
        float r[NN];
        float mx = -INFINITY;
#pragma unroll
        for (int n = 0; n < NN; ++n) {
            r[n] = Ap[tid * NN + n];
            mx = fmaxf(mx, r[n]);
        }
        float s = 0.f;
#pragma unroll
        for (int n = 0; n < NN; ++n) {
            r[n] = expf(r[n] - mx);
            s += r[n];
        }
        float inv = 1.f / s;
#pragma unroll
        for (int n = 0; n < NN; ++n) ws[tid * NN + n] = r[n] * inv;
    }

    // Secant table: bins {tid, tid+256}, both edges computed per bin
    // (same anchoring as R10/R11 -> bit-identical results).
    float bb2 = b2p[0];
    f32x2* __restrict__ tab = (f32x2*)(ws + 64);
#pragma unroll
    for (int i = 0; i < 2; ++i) {
        int k = tid + i * 256;
        float ea = YMIN + (float)k * BINW;
        float eb = ea + BINW;
        float fa = bb2, fb = bb2;
#pragma unroll
        for (int h = 0; h < HH; ++h) {
            float w1 = W1p[h], bv = b1p[h], w2 = W2p[h];
            fa = fmaf(fmaxf(fmaf(w1, ea, bv), 0.f), w2, fa);
            fb = fmaf(fmaxf(fmaf(w1, eb, bv), 0.f), w2, fb);
        }
        float beta = (fb - fa) * INVH;
        tab[k] = mk2(fmaf(-beta, ea, fa), beta);   // alpha anchored at ea
    }
}

// --- Kernel 2: pure stream. One pair (12 floats) per thread. ---
__global__ __launch_bounds__(256, 4) void graph_block_main(
    const float* __restrict__ x,
    const float* __restrict__ ws,
    float* __restrict__ out,
    int nPairs)
{
    const int p = blockIdx.x * 256 + threadIdx.x;
    if (p >= nPairs) return;

    const f32x4* __restrict__ xv = (const f32x4*)x;
    f32x4* __restrict__ ov = (f32x4*)out;

    // 3x dwordx4 at 48B lane stride; the 3 instructions cover the same
    // contiguous window, L1 absorbs the overlap.
    f32x4 v0 = xv[3 * p];
    f32x4 v1 = xv[3 * p + 1];
    f32x4 v2 = xv[3 * p + 2];

    const float* __restrict__ A = ws;                       // uniform -> s_load
    const f32x2* __restrict__ tab = (const f32x2*)(ws + 64); // 4KB, L2-hot

    // xx[n] = (rowA[n], rowB[n]) packed pairs
    f32x2 xx[NN];
    xx[0] = mk2(v0.x, v1.z);
    xx[1] = mk2(v0.y, v1.w);
    xx[2] = mk2(v0.z, v2.x);
    xx[3] = mk2(v0.w, v2.y);
    xx[4] = mk2(v1.x, v2.z);
    xx[5] = mk2(v1.y, v2.w);

    f32x2 yy[NN];
#pragma unroll
    for (int m = 0; m < NN; ++m) {
        f32x2 a = mk2(0.f, 0.f);
#pragma unroll
        for (int n = 0; n < NN; ++n) {
            float c = A[m * NN + n];     // wave-uniform scalar load
            a = pk_fma(mk2(c, c), xx[n], a);
        }
        yy[m] = a;
    }

    f32x2 rr[NN];
#pragma unroll
    for (int m = 0; m < NN; ++m) {
#pragma unroll
        for (int half = 0; half < 2; ++half) {
            float yv = half ? yy[m].y : yy[m].x;
            float fi = fmaf(yv, INVH, OFFS);
            fi = fminf(fmaxf(fi, 0.0f), (float)(NB - 1));   // -> v_med3_f32
            int k = (int)fi;
            f32x2 ab = tab[k];                // global_load_dwordx2, L2 hit
            float r = fmaf(ab.y, yv, ab.x);
            if (half) rr[m].y = r; else rr[m].x = r;
        }
    }

    f32x4 o0, o1, o2;
    o0.x = v0.x + rr[0].x;
    o0.y = v0.y + rr[1].x;
    o0.z = v0.z + rr[2].x;
    o0.w = v0.w + rr[3].x;
    o1.x = v1.x + rr[4].x;
    o1.y = v1.y + rr[5].x;
    o1.z = v1.z + rr[0].y;
    o1.w = v1.w + rr[1].y;
    o2.x = v2.x + rr[2].y;
    o2.y = v2.y + rr[3].y;
    o2.z = v2.z + rr[4].y;
    o2.w = v2.w + rr[5].y;

    ov[3 * p]     = o0;
    ov[3 * p + 1] = o1;
    ov[3 * p + 2] = o2;
}

extern "C" void kernel_launch(void* const* d_in, const int* in_sizes, int n_in,
                              void* d_out, int out_size, void* d_ws, size_t ws_size,
                              hipStream_t stream) {
    const float* x  = (const float*)d_in[0];
    const float* Ap = (const float*)d_in[1];
    const float* W1 = (const float*)d_in[2];
    const float* b1 = (const float*)d_in[3];
    const float* W2 = (const float*)d_in[4];
    const float* b2 = (const float*)d_in[5];
    float* out = (float*)d_out;
    float* ws  = (float*)d_ws;

    prep_kernel<<<1, 256, 0, stream>>>(Ap, W1, b1, W2, b2, ws);

    int nPairs = in_sizes[0] / 12;                 // 524,288 = 2048 * 256
    int grid = (nPairs + 255) / 256;               // 2048 blocks, 1 pair/thread
    graph_block_main<<<grid, 256, 0, stream>>>(x, ws, out, nPairs);
}

// Round 13
// 18.216 us; speedup vs baseline: 1.2283x; 1.2283x over previous
//
#include <hip/hip_runtime.h>
#include <math.h>

// out[b,m] = x[b,m] + f(y[b,m]),  y[b,m] = sum_n softmax(A_param)[m,n] * x[b,n]
// f(y) = b2 + sum_h relu(y*W1[h] + b1[h]) * W2[h]  -- piecewise-linear in y,
// 512-bin secant table (alpha_k, beta_k), anchors identical to R7..R12
// (all passed absmax 0.03125).
//
// R13 structure (vs R7 best=15.9us):
//  - global_load_lds stages x directly into a wave-private 3KB LDS slab slice
//    (no VGPR staging -> peak liveness ~50 regs).
//  - __launch_bounds__(256,8): VGPR<=64 -> 8 blocks/CU, 32 waves/CU, 2048
//    blocks in one residency round with twice the VMEM queue depth.
//  - ONE barrier total. Each thread builds its 2 table bins self-contained
//    (both edges per bin, R12 prep math). After the barrier each wave reads
//    its own slab slice at 48B stride, evals, and stores DIRECT to global --
//    no second LDS trip, no second barrier, no cross-wave coupling.

typedef float f32x2 __attribute__((ext_vector_type(2)));
typedef float f32x4 __attribute__((ext_vector_type(4)));

#define NN 6
#define HH 32
#define NB 512
#define YMIN  (-8.0f)
#define YSPAN (16.0f)
#define INVH  ((float)NB / YSPAN)   // 32.0
#define OFFS  (-YMIN * INVH)        // 256.0
#define BINW  (YSPAN / (float)NB)   // 0.03125

__device__ __forceinline__ f32x2 mk2(float a, float b) {
    f32x2 r; r.x = a; r.y = b; return r;
}

__device__ __forceinline__ f32x2 pk_fma(f32x2 a, f32x2 b, f32x2 c) {
#if __has_builtin(__builtin_elementwise_fma)
    return __builtin_elementwise_fma(a, b, c);
#else
    f32x2 r; r.x = fmaf(a.x, b.x, c.x); r.y = fmaf(a.y, b.y, c.y); return r;
#endif
}

__global__ __launch_bounds__(256, 8) void graph_block_fused(
    const float* __restrict__ x,
    const float* __restrict__ Ap,
    const float* __restrict__ W1p,
    const float* __restrict__ b1p,
    const float* __restrict__ W2p,
    const float* __restrict__ b2p,
    float* __restrict__ out,
    int nPairs)
{
    __shared__ float sA[NN * NN];
    __shared__ __align__(16) f32x2 sTab[NB];
    __shared__ __align__(16) f32x4 slab[768];   // 12KB block chunk, wave-sliced

    const int tid = threadIdx.x;
    const int wid = tid >> 6;
    const int lane = tid & 63;

    const f32x4* __restrict__ xv = (const f32x4*)x;

    // ---- Stage this block's 12KB via global_load_lds: each wave DMAs its
    //      private 3KB slice (3 x 1KB, lane-linear). No VGPR roundtrip.
    {
        const int blockF4 = blockIdx.x * 768;
        const int sliceF4 = wid * 192;
#pragma unroll
        for (int j = 0; j < 3; ++j) {
            const f32x4* g = xv + blockF4 + sliceF4 + j * 64 + lane;
            __builtin_amdgcn_global_load_lds(
                (const __attribute__((address_space(1))) void*)g,
                (__attribute__((address_space(3))) void*)((char*)slab + (sliceF4 + j * 64) * 16),
                16, 0, 0);
        }
    }

    // ---- Row-softmax: lanes 0..5 of wave 0 (runs under the DMA).
    if (tid < NN) {
        float r[NN];
        float mx = -INFINITY;
#pragma unroll
        for (int n = 0; n < NN; ++n) {
            r[n] = Ap[tid * NN + n];
            mx = fmaxf(mx, r[n]);
        }
        float s = 0.f;
#pragma unroll
        for (int n = 0; n < NN; ++n) {
            r[n] = expf(r[n] - mx);
            s += r[n];
        }
        float inv = 1.f / s;
#pragma unroll
        for (int n = 0; n < NN; ++n) sA[tid * NN + n] = r[n] * inv;
    }

    // ---- Secant table, self-contained per thread: bins {tid, tid+256},
    //      BOTH edges computed locally (R12 prep math -> bit-identical).
    //      Params via wave-uniform scalar loads; ~384 fma hides under DMA.
    {
        float bb2 = b2p[0];
#pragma unroll
        for (int i = 0; i < 2; ++i) {
            int k = tid + i * 256;
            float ea = YMIN + (float)k * BINW;
            float eb = ea + BINW;
            float fa = bb2, fb = bb2;
#pragma unroll
            for (int h = 0; h < HH; ++h) {
                float w1 = W1p[h], bv = b1p[h], w2 = W2p[h];
                fa = fmaf(fmaxf(fmaf(w1, ea, bv), 0.f), w2, fa);
                fb = fmaf(fmaxf(fmaf(w1, eb, bv), 0.f), w2, fb);
            }
            float beta = (fb - fa) * INVH;
            sTab[k] = mk2(fmaf(-beta, ea, fa), beta);   // alpha anchored at ea
        }
    }
    __syncthreads();   // the ONLY barrier (drains DMA vmcnt + publishes sA/sTab)

    // ---- Own pair from the wave's slab slice (48B lane stride; a wave's 256
    //      words spread evenly across all 32 banks).
    const int p = blockIdx.x * 256 + tid;              // global pair index
    const f32x4* ps = slab + (size_t)tid * 3;
    f32x4 v0 = ps[0];
    f32x4 v1 = ps[1];
    f32x4 v2 = ps[2];

    // xx[n] = (rowA[n], rowB[n]) packed pairs
    f32x2 xx[NN];
    xx[0] = mk2(v0.x, v1.z);
    xx[1] = mk2(v0.y, v1.w);
    xx[2] = mk2(v0.z, v2.x);
    xx[3] = mk2(v0.w, v2.y);
    xx[4] = mk2(v1.x, v2.z);
    xx[5] = mk2(v1.y, v2.w);

    f32x2 yy[NN];
#pragma unroll
    for (int m = 0; m < NN; ++m) {
        f32x2 a = mk2(0.f, 0.f);
#pragma unroll
        for (int n = 0; n < NN; ++n) {
            float c = sA[m * NN + n];    // uniform-address LDS broadcast
            a = pk_fma(mk2(c, c), xx[n], a);
        }
        yy[m] = a;
    }

    f32x2 rr[NN];
#pragma unroll
    for (int m = 0; m < NN; ++m) {
#pragma unroll
        for (int half = 0; half < 2; ++half) {
            float yv = half ? yy[m].y : yy[m].x;
            float fi = fmaf(yv, INVH, OFFS);
            fi = fminf(fmaxf(fi, 0.0f), (float)(NB - 1));   // -> v_med3_f32
            int k = (int)fi;
            f32x2 ab = sTab[k];               // ds_read_b64 gather
            float r = fmaf(ab.y, yv, ab.x);
            if (half) rr[m].y = r; else rr[m].x = r;
        }
    }

    f32x4 o0, o1, o2;
    o0.x = v0.x + rr[0].x;
    o0.y = v0.y + rr[1].x;
    o0.z = v0.z + rr[2].x;
    o0.w = v0.w + rr[3].x;
    o1.x = v1.x + rr[4].x;
    o1.y = v1.y + rr[5].x;
    o1.z = v1.z + rr[0].y;
    o1.w = v1.w + rr[1].y;
    o2.x = v2.x + rr[2].y;
    o2.y = v2.y + rr[3].y;
    o2.z = v2.z + rr[4].y;
    o2.w = v2.w + rr[5].y;

    // ---- Direct 48B-lane-stride stores (3 instrs cover one contiguous 3KB
    //      window per wave; L2 write-combines to full lines). No 2nd barrier.
    f32x4* __restrict__ ov = (f32x4*)out;
    ov[3 * p]     = o0;
    ov[3 * p + 1] = o1;
    ov[3 * p + 2] = o2;
}

extern "C" void kernel_launch(void* const* d_in, const int* in_sizes, int n_in,
                              void* d_out, int out_size, void* d_ws, size_t ws_size,
                              hipStream_t stream) {
    const float* x  = (const float*)d_in[0];
    const float* Ap = (const float*)d_in[1];
    const float* W1 = (const float*)d_in[2];
    const float* b1 = (const float*)d_in[3];
    const float* W2 = (const float*)d_in[4];
    const float* b2 = (const float*)d_in[5];
    float* out = (float*)d_out;

    int nPairs = in_sizes[0] / 12;                 // 524,288 = 2048 * 256 exactly
    int grid = (nPairs + 255) / 256;               // 2048 blocks, 8/CU, one round
    graph_block_fused<<<grid, 256, 0, stream>>>(x, Ap, W1, b1, W2, b2, out, nPairs);
}

// Round 14
// 16.489 us; speedup vs baseline: 1.3570x; 1.1048x over previous
//
#include <hip/hip_runtime.h>
#include <math.h>

// out[b,m] = x[b,m] + f(y[b,m]),  y[b,m] = sum_n softmax(A_param)[m,n] * x[b,n]
// f(y) = b2 + sum_h relu(y*W1[h] + b1[h]) * W2[h]  -- piecewise-linear in y,
// 512-bin secant table (alpha_k, beta_k); anchors identical to R7..R13
// (absmax 0.03125 in every passing round).
//
// R14 = R7 (best measured, 15.9us) with the barrier count cut 4 -> 2:
//  - table build is self-contained per thread (scalar-loaded params, both
//    edges per bin; R11/R13-proven bit-identical) -> no param-staging barrier,
//    no edge/bin phase barrier.
//  - data path is R7's EXACT winner: unit-stride float4 global loads ->
//    block slab (LDS) -> 48B-slot eval in place -> unit-stride stores.
// This is the final within-family A/B: if it ties R7, the residual is fixed
// launch/replay overhead on top of the ~8.4us stream and we are at the wall.

typedef float f32x2 __attribute__((ext_vector_type(2)));
typedef float f32x4 __attribute__((ext_vector_type(4)));

#define NN 6
#define HH 32
#define NB 512
#define YMIN  (-8.0f)
#define YSPAN (16.0f)
#define INVH  ((float)NB / YSPAN)   // 32.0
#define OFFS  (-YMIN * INVH)        // 256.0
#define BINW  (YSPAN / (float)NB)   // 0.03125
#define CPB   2                     // chunks per block (256 pairs each)
#define F4C   768                   // float4 per chunk (256 pairs * 48B)

__device__ __forceinline__ f32x2 mk2(float a, float b) {
    f32x2 r; r.x = a; r.y = b; return r;
}

__device__ __forceinline__ f32x2 pk_fma(f32x2 a, f32x2 b, f32x2 c) {
#if __has_builtin(__builtin_elementwise_fma)
    return __builtin_elementwise_fma(a, b, c);
#else
    f32x2 r; r.x = fmaf(a.x, b.x, c.x); r.y = fmaf(a.y, b.y, c.y); return r;
#endif
}

// Row-mix + table lookup + residual for one pair (12 floats in v0..v2).
__device__ __forceinline__ void eval_pair(
    f32x4 v0, f32x4 v1, f32x4 v2,
    const float* __restrict__ sA,
    const f32x2* __restrict__ sTab,
    f32x4& o0, f32x4& o1, f32x4& o2)
{
    f32x2 xx[NN];
    xx[0] = mk2(v0.x, v1.z);
    xx[1] = mk2(v0.y, v1.w);
    xx[2] = mk2(v0.z, v2.x);
    xx[3] = mk2(v0.w, v2.y);
    xx[4] = mk2(v1.x, v2.z);
    xx[5] = mk2(v1.y, v2.w);

    f32x2 yy[NN];
#pragma unroll
    for (int m = 0; m < NN; ++m) {
        f32x2 a = mk2(0.f, 0.f);
#pragma unroll
        for (int n = 0; n < NN; ++n) {
            float c = sA[m * NN + n];    // uniform-address LDS broadcast
            a = pk_fma(mk2(c, c), xx[n], a);
        }
        yy[m] = a;
    }

    f32x2 rr[NN];
#pragma unroll
    for (int m = 0; m < NN; ++m) {
#pragma unroll
        for (int half = 0; half < 2; ++half) {
            float yv = half ? yy[m].y : yy[m].x;
            float fi = fmaf(yv, INVH, OFFS);
            fi = fminf(fmaxf(fi, 0.0f), (float)(NB - 1));   // -> v_med3_f32
            int k = (int)fi;
            f32x2 ab = sTab[k];               // ds_read_b64 gather
            float r = fmaf(ab.y, yv, ab.x);
            if (half) rr[m].y = r; else rr[m].x = r;
        }
    }

    o0.x = v0.x + rr[0].x;
    o0.y = v0.y + rr[1].x;
    o0.z = v0.z + rr[2].x;
    o0.w = v0.w + rr[3].x;
    o1.x = v1.x + rr[4].x;
    o1.y = v1.y + rr[5].x;
    o1.z = v1.z + rr[0].y;
    o1.w = v1.w + rr[1].y;
    o2.x = v2.x + rr[2].y;
    o2.y = v2.y + rr[3].y;
    o2.z = v2.z + rr[4].y;
    o2.w = v2.w + rr[5].y;
}

__global__ __launch_bounds__(256, 4) void graph_block_fused(
    const float* __restrict__ x,
    const float* __restrict__ Ap,
    const float* __restrict__ W1p,
    const float* __restrict__ b1p,
    const float* __restrict__ W2p,
    const float* __restrict__ b2p,
    float* __restrict__ out,
    int nF4)
{
    __shared__ float sA[NN * NN];
    __shared__ __align__(16) f32x2 sTab[NB];
    __shared__ __align__(16) float sX[CPB][F4C * 4];   // 2 x 12KB

    const int tid = threadIdx.x;
    const int blockF4 = blockIdx.x * (CPB * F4C);

    // ---- Issue ALL x loads up front (unit-stride float4; the HBM latency
    //      drains under the softmax/table build below).
    f32x4 st[CPB][3];
#pragma unroll
    for (int c = 0; c < CPB; ++c)
#pragma unroll
        for (int j = 0; j < 3; ++j) {
            int f4 = blockF4 + c * F4C + j * 256 + tid;
            if (f4 < nF4) st[c][j] = ((const f32x4*)x)[f4];
        }

    // ---- Row-softmax: threads 0..5.
    if (tid < NN) {
        float r[NN];
        float mx = -INFINITY;
#pragma unroll
        for (int n = 0; n < NN; ++n) {
            r[n] = Ap[tid * NN + n];
            mx = fmaxf(mx, r[n]);
        }
        float s = 0.f;
#pragma unroll
        for (int n = 0; n < NN; ++n) {
            r[n] = expf(r[n] - mx);
            s += r[n];
        }
        float inv = 1.f / s;
#pragma unroll
        for (int n = 0; n < NN; ++n) sA[tid * NN + n] = r[n] * inv;
    }

    // ---- Secant table, self-contained per thread: bins {tid, tid+256},
    //      both edges computed locally from scalar-loaded params
    //      (R11/R13-proven bit-identical; ~384 fma hidden under load latency).
    {
        float bb2 = b2p[0];
#pragma unroll
        for (int i = 0; i < 2; ++i) {
            int k = tid + i * 256;
            float ea = YMIN + (float)k * BINW;
            float eb = ea + BINW;
            float fa = bb2, fb = bb2;
#pragma unroll
            for (int h = 0; h < HH; ++h) {
                float w1 = W1p[h], bv = b1p[h], w2 = W2p[h];
                fa = fmaf(fmaxf(fmaf(w1, ea, bv), 0.f), w2, fa);
                fb = fmaf(fmaxf(fmaf(w1, eb, bv), 0.f), w2, fb);
            }
            float beta = (fb - fa) * INVH;
            sTab[k] = mk2(fmaf(-beta, ea, fa), beta);   // alpha anchored at ea
        }
    }

    // ---- Stage x into the slab (unit-stride ds_write_b128).
#pragma unroll
    for (int c = 0; c < CPB; ++c)
#pragma unroll
        for (int j = 0; j < 3; ++j)
            ((f32x4*)sX[c])[j * 256 + tid] = st[c][j];
    __syncthreads();   // (A) sA + sTab + staged x all published

    // ---- Eval both chunks in place (thread-exclusive 48B slots; a wave's
    //      256 words spread evenly across all 32 banks).
#pragma unroll
    for (int c = 0; c < CPB; ++c) {
        f32x4* ps = (f32x4*)sX[c] + tid * 3;
        f32x4 v0 = ps[0], v1 = ps[1], v2 = ps[2];
        f32x4 o0, o1, o2;
        eval_pair(v0, v1, v2, sA, sTab, o0, o1, o2);
        ps[0] = o0; ps[1] = o1; ps[2] = o2;
    }
    __syncthreads();   // (B) results visible

    // ---- Unit-stride float4 stores.
#pragma unroll
    for (int c = 0; c < CPB; ++c)
#pragma unroll
        for (int j = 0; j < 3; ++j) {
            int f4 = blockF4 + c * F4C + j * 256 + tid;
            if (f4 < nF4) ((f32x4*)out)[f4] = ((const f32x4*)sX[c])[j * 256 + tid];
        }
}

extern "C" void kernel_launch(void* const* d_in, const int* in_sizes, int n_in,
                              void* d_out, int out_size, void* d_ws, size_t ws_size,
                              hipStream_t stream) {
    const float* x  = (const float*)d_in[0];
    const float* Ap = (const float*)d_in[1];
    const float* W1 = (const float*)d_in[2];
    const float* b1 = (const float*)d_in[3];
    const float* W2 = (const float*)d_in[4];
    const float* b2 = (const float*)d_in[5];
    float* out = (float*)d_out;

    int nF4 = in_sizes[0] / 4;                    // 1,572,864
    int perBlock = CPB * F4C;                     // 1536 float4 per block
    int grid = (nF4 + perBlock - 1) / perBlock;   // 1024 blocks = 4/CU, 1 round
    graph_block_fused<<<grid, 256, 0, stream>>>(x, Ap, W1, b1, W2, b2, out, nF4);
}